// Round 2
// baseline (827.989 us; speedup 1.0000x reference)
//
#include <hip/hip_runtime.h>

// SelfAttention (B=4, C=128, H=W=64), fp32 I/O.
// out[b,c,i] = X[b,c,i] + sum_j softmax_over_i(QK^T)[i,j] * V[j,c]
// fp32-faithful via split-bf16 (hi+lo) 3-term MFMA emulation on
// mfma_f32_16x16x32_bf16 (CDNA4 has no fp32 MFMA).

typedef unsigned short u16;
typedef __attribute__((ext_vector_type(8))) __bf16 bf16x8;
typedef __attribute__((ext_vector_type(8))) unsigned short us8;
typedef __attribute__((ext_vector_type(4))) float f32x4;

#define NB 4
#define CH 128
#define NP 4096
#define VPAD 40    // 32 + 8 u16: LDS row stride for P scratch

__device__ __forceinline__ float bf2f(u16 b){ union{float f;unsigned u;}v; v.u=((unsigned)b)<<16; return v.f; }
__device__ __forceinline__ u16 f2bf(float f){ union{float f;unsigned u;}v; v.f=f; unsigned r=v.u + 0x7FFFu + ((v.u>>16)&1u); return (u16)(r>>16); }

__device__ __forceinline__ f32x4 mfma16(bf16x8 a, bf16x8 b, f32x4 c){
  return __builtin_amdgcn_mfma_f32_16x16x32_bf16(a, b, c, 0, 0, 0);
}
__device__ __forceinline__ bf16x8 ld8(const u16* p){
  union { us8 u; bf16x8 b; } v; v.u = *(const us8*)p; return v.b;
}
// fp32[8] -> (hi, lo) bf16x8 pair: x = hi + lo + O(2^-18 x)
__device__ __forceinline__ void split8(const float* p, bf16x8& h, bf16x8& l){
  union { us8 u; bf16x8 b; } uh, ul;
  #pragma unroll
  for (int e=0;e<8;++e){
    float f = p[e];
    u16 hb = f2bf(f);
    uh.u[e] = hb;
    ul.u[e] = f2bf(f - bf2f(hb));
  }
  h = uh.b; l = ul.b;
}

// ---------------------------------------------------------------------------
// Kernel 1: projections. One wave per 16-pixel tile.
// Q[i][c] = sum_c' X[c'][i] Wq[c][c'] + bq[c]  (K same); Vt[c][j] likewise,
// stored transposed. Outputs pre-split into bf16 hi/lo arrays.
// ---------------------------------------------------------------------------
__global__ __launch_bounds__(64) void proj_kernel(
    const float* __restrict__ X,
    const float* __restrict__ Wq, const float* __restrict__ bq,
    const float* __restrict__ Wk, const float* __restrict__ bk,
    const float* __restrict__ Wv, const float* __restrict__ bv,
    u16* __restrict__ Qhi, u16* __restrict__ Qlo,
    u16* __restrict__ Khi, u16* __restrict__ Klo,
    u16* __restrict__ Vthi, u16* __restrict__ Vtlo)
{
  __shared__ float XT[16][CH+4];     // [pixel][c]
  const int b = blockIdx.y, p0 = blockIdx.x*16, lane = threadIdx.x;
  #pragma unroll
  for (int h=0; h<2; ++h){
    int c = lane + h*64;
    const float* src = X + ((size_t)b*CH + c)*NP + p0;
    #pragma unroll
    for (int v4=0; v4<4; ++v4){
      f32x4 v = *(const f32x4*)(src + v4*4);
      #pragma unroll
      for (int p=0;p<4;++p) XT[v4*4+p][c] = v[p];
    }
  }
  __syncthreads();
  const int l15 = lane&15, quad = lane>>4;
  bf16x8 xh[4], xl[4];               // X tile fragments (A for Q/K, B for Vt)
  #pragma unroll
  for (int s=0;s<4;++s) split8(&XT[l15][s*32+quad*8], xh[s], xl[s]);

  const float* Wm[2] = {Wq, Wk};
  const float* bm[2] = {bq, bk};
  u16* OH[2] = {Qhi, Khi};
  u16* OL[2] = {Qlo, Klo};
  #pragma unroll
  for (int m=0;m<2;++m){
    #pragma unroll
    for (int nt=0;nt<8;++nt){
      f32x4 a = {0.f,0.f,0.f,0.f};
      #pragma unroll
      for (int s=0;s<4;++s){
        bf16x8 wh, wl;
        split8(&Wm[m][(size_t)(nt*16+l15)*CH + s*32 + quad*8], wh, wl);
        a = mfma16(xh[s], wl, a);
        a = mfma16(xl[s], wh, a);
        a = mfma16(xh[s], wh, a);
      }
      int o = nt*16 + l15;
      float bias = bm[m][o];
      #pragma unroll
      for (int r=0;r<4;++r){
        int i = p0 + quad*4 + r;
        float q = a[r] + bias;
        u16 hb = f2bf(q);
        size_t idx = ((size_t)b*NP + i)*CH + o;
        OH[m][idx] = hb;
        OL[m][idx] = f2bf(q - bf2f(hb));
      }
    }
  }
  #pragma unroll
  for (int mt=0;mt<8;++mt){          // Vt = Wv * X, D[m=c_out][n=pixel]
    f32x4 a = {0.f,0.f,0.f,0.f};
    #pragma unroll
    for (int s=0;s<4;++s){
      bf16x8 wh, wl;
      split8(&Wv[(size_t)(mt*16+l15)*CH + s*32 + quad*8], wh, wl);
      a = mfma16(wh, xl[s], a);
      a = mfma16(wl, xh[s], a);
      a = mfma16(wh, xh[s], a);
    }
    #pragma unroll
    for (int r=0;r<4;++r){
      int co = mt*16 + quad*4 + r;
      float v = a[r] + bv[co];
      u16 hb = f2bf(v);
      size_t idx = ((size_t)b*CH + co)*NP + p0 + l15;
      Vthi[idx] = hb;
      Vtlo[idx] = f2bf(v - bf2f(hb));
    }
  }
}

// ---------------------------------------------------------------------------
// Kernel 2: colrinv[j] = 1 / sum_i exp(S[i][j]).  No max-subtraction needed:
// |S| <~ 25 so exp stays in fp32 range.  Block = 64 key columns, all i.
// K fragments live in registers; Q streams from L2/L3.
// ---------------------------------------------------------------------------
__global__ __launch_bounds__(256) void stats_kernel(
    const u16* __restrict__ Qhi, const u16* __restrict__ Qlo,
    const u16* __restrict__ Khi, const u16* __restrict__ Klo,
    float* __restrict__ colrinv)
{
  __shared__ float wsum[4][64];
  const int b = blockIdx.y, j0 = blockIdx.x*64;
  const int tid = threadIdx.x, lane = tid&63, w = tid>>6;
  const int l15 = lane&15, quad = lane>>4;
  bf16x8 kh[4][4], kl[4][4];
  #pragma unroll
  for (int js=0;js<4;++js)
    #pragma unroll
    for (int s=0;s<4;++s){
      size_t g = ((size_t)b*NP + j0 + js*16 + l15)*CH + s*32 + quad*8;
      kh[js][s] = ld8(&Khi[g]);
      kl[js][s] = ld8(&Klo[g]);
    }
  float lsum[4] = {0.f,0.f,0.f,0.f};
  for (int it=0; it<64; ++it){
    int i0 = it*64 + w*16;
    bf16x8 qh[4], ql[4];
    #pragma unroll
    for (int s=0;s<4;++s){
      size_t g = ((size_t)b*NP + i0 + l15)*CH + s*32 + quad*8;
      qh[s] = ld8(&Qhi[g]); ql[s] = ld8(&Qlo[g]);
    }
    #pragma unroll
    for (int js=0;js<4;++js){
      f32x4 s4 = {0.f,0.f,0.f,0.f};
      #pragma unroll
      for (int s=0;s<4;++s){
        s4 = mfma16(qh[s], kl[js][s], s4);
        s4 = mfma16(ql[s], kh[js][s], s4);
        s4 = mfma16(qh[s], kh[js][s], s4);
      }
      lsum[js] += __expf(s4[0])+__expf(s4[1])+__expf(s4[2])+__expf(s4[3]);
    }
  }
  #pragma unroll
  for (int js=0;js<4;++js){
    lsum[js] += __shfl_xor(lsum[js], 16);
    lsum[js] += __shfl_xor(lsum[js], 32);
  }
  if (lane < 16){
    #pragma unroll
    for (int js=0;js<4;++js) wsum[w][js*16 + lane] = lsum[js];
  }
  __syncthreads();
  if (tid < 64){
    float t = wsum[0][tid]+wsum[1][tid]+wsum[2][tid]+wsum[3][tid];
    colrinv[(size_t)b*NP + j0 + tid] = 1.0f/t;
  }
}

// ---------------------------------------------------------------------------
// Kernel 3: out[b][c][i] = X[b][c][i] + sum_j exp(S[i][j])*colrinv[j]*V[j][c]
// One wave owns 16 query rows; loops over all 128 j-tiles of 32.
// Waves independent (no block barriers); P goes through per-wave LDS to
// convert C/D layout -> A layout, split hi/lo for the PV MFMA.
// ---------------------------------------------------------------------------
__global__ __launch_bounds__(256) void attn_kernel(
    const float* __restrict__ X,
    const u16* __restrict__ Qhi, const u16* __restrict__ Qlo,
    const u16* __restrict__ Khi, const u16* __restrict__ Klo,
    const u16* __restrict__ Vthi, const u16* __restrict__ Vtlo,
    const float* __restrict__ colrinv, float* __restrict__ out)
{
  __shared__ u16 Psh[4][16*VPAD], Psl[4][16*VPAD];
  const int b = blockIdx.y;
  const int tid = threadIdx.x, lane = tid&63, w = tid>>6;
  const int l15 = lane&15, quad = lane>>4;
  const int iw = blockIdx.x*64 + w*16;

  bf16x8 qh[4], ql[4];
  #pragma unroll
  for (int s=0;s<4;++s){
    size_t g = ((size_t)b*NP + iw + l15)*CH + s*32 + quad*8;
    qh[s] = ld8(&Qhi[g]); ql[s] = ld8(&Qlo[g]);
  }
  f32x4 acc[8];
  #pragma unroll
  for (int ct=0;ct<8;++ct) acc[ct] = (f32x4){0.f,0.f,0.f,0.f};
  const float* cr = colrinv + (size_t)b*NP;

  for (int jt=0; jt<128; ++jt){
    int j0 = jt*32;
    #pragma unroll
    for (int js=0;js<2;++js){
      f32x4 s4 = {0.f,0.f,0.f,0.f};
      #pragma unroll
      for (int s=0;s<4;++s){
        size_t g = ((size_t)b*NP + j0 + js*16 + l15)*CH + s*32 + quad*8;
        bf16x8 kbh = ld8(&Khi[g]);
        bf16x8 kbl = ld8(&Klo[g]);
        s4 = mfma16(qh[s], kbl, s4);
        s4 = mfma16(ql[s], kbh, s4);
        s4 = mfma16(qh[s], kbh, s4);
      }
      float rj = cr[j0 + js*16 + l15];
      #pragma unroll
      for (int r=0;r<4;++r){
        float p = __expf(s4[r]) * rj;          // P in [0,1]
        u16 hb = f2bf(p);
        int row = quad*4 + r;
        Psh[w][row*VPAD + js*16 + l15] = hb;
        Psl[w][row*VPAD + js*16 + l15] = f2bf(p - bf2f(hb));
      }
    }
    __asm__ volatile("s_waitcnt lgkmcnt(0)" ::: "memory");  // wave-local LDS RAW
    bf16x8 pah = ld8(&Psh[w][l15*VPAD + quad*8]);
    bf16x8 pal = ld8(&Psl[w][l15*VPAD + quad*8]);
    #pragma unroll
    for (int ct=0;ct<8;++ct){
      size_t g = ((size_t)b*CH + ct*16 + l15)*NP + j0 + quad*8;
      bf16x8 vbh = ld8(&Vthi[g]);
      bf16x8 vbl = ld8(&Vtlo[g]);
      acc[ct] = mfma16(pah, vbl, acc[ct]);
      acc[ct] = mfma16(pal, vbh, acc[ct]);
      acc[ct] = mfma16(pah, vbh, acc[ct]);
    }
  }
  // fused residual epilogue, fp32 out
  const size_t bofs = (size_t)b*CH*NP;
  #pragma unroll
  for (int ct=0;ct<8;++ct){
    int c = ct*16 + l15;
    size_t o = bofs + (size_t)c*NP + iw + quad*4;
    f32x4 xv = *(const f32x4*)&X[o];
    f32x4 r;
    #pragma unroll
    for (int e=0;e<4;++e) r[e] = xv[e] + acc[ct][e];
    *(f32x4*)&out[o] = r;
  }
}

extern "C" void kernel_launch(void* const* d_in, const int* in_sizes, int n_in,
                              void* d_out, int out_size, void* d_ws, size_t ws_size,
                              hipStream_t stream)
{
  const float* X  = (const float*)d_in[0];
  const float* Wq = (const float*)d_in[1];
  const float* bq = (const float*)d_in[2];
  const float* Wk = (const float*)d_in[3];
  const float* bk = (const float*)d_in[4];
  const float* Wv = (const float*)d_in[5];
  const float* bv = (const float*)d_in[6];
  float* outp = (float*)d_out;

  const size_t n = (size_t)NB*NP*CH;        // 2,097,152
  u16* Qhi = (u16*)d_ws;
  u16* Qlo = Qhi + n;
  u16* Khi = Qlo + n;
  u16* Klo = Khi + n;
  u16* Vthi = Klo + n;
  u16* Vtlo = Vthi + n;
  float* colrinv = (float*)(Vtlo + n);      // 24 MB + 64 KB total ws

  proj_kernel <<<dim3(NP/16, NB),  64, 0, stream>>>(X, Wq,bq, Wk,bk, Wv,bv,
                                                    Qhi,Qlo, Khi,Klo, Vthi,Vtlo);
  stats_kernel<<<dim3(NP/64, NB), 256, 0, stream>>>(Qhi,Qlo, Khi,Klo, colrinv);
  attn_kernel <<<dim3(NP/64, NB), 256, 0, stream>>>(X, Qhi,Qlo, Khi,Klo, Vthi,Vtlo,
                                                    colrinv, outp);
}

// Round 3
// 398.657 us; speedup vs baseline: 2.0769x; 2.0769x over previous
//
#include <hip/hip_runtime.h>

// SelfAttention (B=4, C=128, H=W=64), fp32 I/O.
// out[b,c,i] = X[b,c,i] + sum_j exp(S[i,j]) * rinv_j * V[j,c],
//   S = Q K^T, rinv_j = 1/sum_i exp(S[i,j])   (softmax over query axis)
// fp32-faithful via split-bf16 (hi+lo) 3-term MFMA emulation.

typedef unsigned short u16;
typedef __attribute__((ext_vector_type(8))) __bf16 bf16x8;
typedef __attribute__((ext_vector_type(8))) unsigned short us8;
typedef __attribute__((ext_vector_type(4))) float f32x4;

#define NB 4
#define CH 128
#define NP 4096
#define KPAD 136   // 128+8 u16 row stride (2-way LDS banks = free)
#define VPAD 40    // 32+8 u16
#define PPAD 36    // 32+4 u16: makes P b16 writes 2-way too

__device__ __forceinline__ float bf2f(u16 b){ union{float f;unsigned u;}v; v.u=((unsigned)b)<<16; return v.f; }
__device__ __forceinline__ u16 f2bf(float f){ union{float f;unsigned u;}v; v.f=f; unsigned r=v.u + 0x7FFFu + ((v.u>>16)&1u); return (u16)(r>>16); }

__device__ __forceinline__ f32x4 mfma16(bf16x8 a, bf16x8 b, f32x4 c){
  return __builtin_amdgcn_mfma_f32_16x16x32_bf16(a, b, c, 0, 0, 0);
}
__device__ __forceinline__ bf16x8 ld8(const u16* p){
  union { us8 u; bf16x8 b; } v; v.u = *(const us8*)p; return v.b;
}
__device__ __forceinline__ void split8(const float* p, bf16x8& h, bf16x8& l){
  union { us8 u; bf16x8 b; } uh, ul;
  #pragma unroll
  for (int e=0;e<8;++e){
    float f = p[e];
    u16 hb = f2bf(f);
    uh.u[e] = hb;
    ul.u[e] = f2bf(f - bf2f(hb));
  }
  h = uh.b; l = ul.b;
}

// ---------------------------------------------------------------------------
// Kernel 0: pre-split the three 128x128 weight matrices into bf16 hi/lo.
// ---------------------------------------------------------------------------
__global__ __launch_bounds__(256) void wsplit_kernel(
    const float* __restrict__ Wq, const float* __restrict__ Wk,
    const float* __restrict__ Wv, u16* __restrict__ Whi, u16* __restrict__ Wlo)
{
  const int m = blockIdx.y;
  const float* W = (m==0) ? Wq : (m==1) ? Wk : Wv;
  int i = blockIdx.x*256 + threadIdx.x;
  float f = W[i];
  u16 hb = f2bf(f);
  Whi[m*CH*CH + i] = hb;
  Wlo[m*CH*CH + i] = f2bf(f - bf2f(hb));
}

// ---------------------------------------------------------------------------
// Kernel 1: projections (one wave per 16-pixel tile), W pre-split.
// ---------------------------------------------------------------------------
__global__ __launch_bounds__(64) void proj_kernel(
    const float* __restrict__ X,
    const u16* __restrict__ Whi, const u16* __restrict__ Wlo,
    const float* __restrict__ bq, const float* __restrict__ bk,
    const float* __restrict__ bv,
    u16* __restrict__ Qhi, u16* __restrict__ Qlo,
    u16* __restrict__ Khi, u16* __restrict__ Klo,
    u16* __restrict__ Vthi, u16* __restrict__ Vtlo)
{
  __shared__ float XT[16][CH+4];
  const int b = blockIdx.y, p0 = blockIdx.x*16, lane = threadIdx.x;
  #pragma unroll
  for (int h=0; h<2; ++h){
    int c = lane + h*64;
    const float* src = X + ((size_t)b*CH + c)*NP + p0;
    #pragma unroll
    for (int v4=0; v4<4; ++v4){
      f32x4 v = *(const f32x4*)(src + v4*4);
      #pragma unroll
      for (int p=0;p<4;++p) XT[v4*4+p][c] = v[p];
    }
  }
  __syncthreads();
  const int l15 = lane&15, quad = lane>>4;
  bf16x8 xh[4], xl[4];
  #pragma unroll
  for (int s=0;s<4;++s) split8(&XT[l15][s*32+quad*8], xh[s], xl[s]);

  const float* bm[2] = {bq, bk};
  u16* OH[2] = {Qhi, Khi};
  u16* OL[2] = {Qlo, Klo};
  #pragma unroll
  for (int m=0;m<2;++m){
    const u16* WH = Whi + m*CH*CH;
    const u16* WL = Wlo + m*CH*CH;
    #pragma unroll
    for (int nt=0;nt<8;++nt){
      f32x4 a = {0.f,0.f,0.f,0.f};
      #pragma unroll
      for (int s=0;s<4;++s){
        size_t g = (size_t)(nt*16+l15)*CH + s*32 + quad*8;
        bf16x8 wh = ld8(&WH[g]), wl = ld8(&WL[g]);
        a = mfma16(xh[s], wl, a);
        a = mfma16(xl[s], wh, a);
        a = mfma16(xh[s], wh, a);
      }
      int o = nt*16 + l15;
      float bias = bm[m][o];
      #pragma unroll
      for (int r=0;r<4;++r){
        int i = p0 + quad*4 + r;
        float q = a[r] + bias;
        u16 hb = f2bf(q);
        size_t idx = ((size_t)b*NP + i)*CH + o;
        OH[m][idx] = hb;
        OL[m][idx] = f2bf(q - bf2f(hb));
      }
    }
  }
  const u16* WH = Whi + 2*CH*CH;
  const u16* WL = Wlo + 2*CH*CH;
  #pragma unroll
  for (int mt=0;mt<8;++mt){
    f32x4 a = {0.f,0.f,0.f,0.f};
    #pragma unroll
    for (int s=0;s<4;++s){
      size_t g = (size_t)(mt*16+l15)*CH + s*32 + quad*8;
      bf16x8 wh = ld8(&WH[g]), wl = ld8(&WL[g]);
      a = mfma16(wh, xl[s], a);
      a = mfma16(wl, xh[s], a);
      a = mfma16(wh, xh[s], a);
    }
    #pragma unroll
    for (int r=0;r<4;++r){
      int co = mt*16 + quad*4 + r;
      float v = a[r] + bv[co];
      u16 hb = f2bf(v);
      size_t idx = ((size_t)b*CH + co)*NP + p0 + l15;
      Vthi[idx] = hb;
      Vtlo[idx] = f2bf(v - bf2f(hb));
    }
  }
}

// ---------------------------------------------------------------------------
// Kernel 2: partial column sums. Block = 64 j x 1024 i. K frags in registers.
// colpart[isplit][b][j] = sum_{i in chunk} exp(S[i][j])
// ---------------------------------------------------------------------------
__global__ __launch_bounds__(256,2) void stats_kernel(
    const u16* __restrict__ Qhi, const u16* __restrict__ Qlo,
    const u16* __restrict__ Khi, const u16* __restrict__ Klo,
    float* __restrict__ colpart)
{
  __shared__ float wsum[4][64];
  const int b = blockIdx.z, isplit = blockIdx.y, j0 = blockIdx.x*64;
  const int tid = threadIdx.x, lane = tid&63, w = tid>>6;
  const int l15 = lane&15, quad = lane>>4;

  bf16x8 kh[4][4], kl[4][4];
  #pragma unroll
  for (int js=0;js<4;++js)
    #pragma unroll
    for (int s=0;s<4;++s){
      size_t g = ((size_t)b*NP + j0 + js*16 + l15)*CH + s*32 + quad*8;
      kh[js][s] = ld8(&Khi[g]);
      kl[js][s] = ld8(&Klo[g]);
    }

  const int ibase = isplit*1024 + w*256;
  bf16x8 qh[4], ql[4], qhn[4], qln[4];
  #pragma unroll
  for (int s=0;s<4;++s){
    size_t g = ((size_t)b*NP + ibase + l15)*CH + s*32 + quad*8;
    qh[s] = ld8(&Qhi[g]); ql[s] = ld8(&Qlo[g]);
  }
  float lsum[4] = {0.f,0.f,0.f,0.f};
  for (int it=0; it<16; ++it){
    if (it < 15){
      int i0 = ibase + (it+1)*16;
      #pragma unroll
      for (int s=0;s<4;++s){
        size_t g = ((size_t)b*NP + i0 + l15)*CH + s*32 + quad*8;
        qhn[s] = ld8(&Qhi[g]); qln[s] = ld8(&Qlo[g]);
      }
    }
    #pragma unroll
    for (int js=0;js<4;++js){
      f32x4 s4 = {0.f,0.f,0.f,0.f};
      #pragma unroll
      for (int s=0;s<4;++s){
        s4 = mfma16(qh[s], kl[js][s], s4);
        s4 = mfma16(ql[s], kh[js][s], s4);
        s4 = mfma16(qh[s], kh[js][s], s4);
      }
      lsum[js] += __expf(s4[0])+__expf(s4[1])+__expf(s4[2])+__expf(s4[3]);
    }
    #pragma unroll
    for (int s=0;s<4;++s){ qh[s]=qhn[s]; ql[s]=qln[s]; }
  }
  #pragma unroll
  for (int js=0;js<4;++js){
    lsum[js] += __shfl_xor(lsum[js], 16);
    lsum[js] += __shfl_xor(lsum[js], 32);
  }
  if (lane < 16){
    #pragma unroll
    for (int js=0;js<4;++js) wsum[w][js*16 + lane] = lsum[js];
  }
  __syncthreads();
  if (tid < 64){
    float t = wsum[0][tid]+wsum[1][tid]+wsum[2][tid]+wsum[3][tid];
    colpart[((size_t)(isplit*NB + b))*NP + j0 + tid] = t;
  }
}

// ---------------------------------------------------------------------------
// Kernel 3a: rinv[b][j] = 1 / sum_isplit colpart
// ---------------------------------------------------------------------------
__global__ __launch_bounds__(256) void rinv_kernel(
    const float* __restrict__ colpart, float* __restrict__ rinv)
{
  int idx = blockIdx.x*256 + threadIdx.x;        // NB*NP = 16384
  int b = idx >> 12, j = idx & (NP-1);
  float s = 0.f;
  #pragma unroll
  for (int k=0;k<4;++k) s += colpart[((size_t)(k*NB + b))*NP + j];
  rinv[idx] = 1.0f / s;
}

// ---------------------------------------------------------------------------
// Kernel 3b: in-place V' = rinv_j * V   (hi/lo re-split)
// ---------------------------------------------------------------------------
__global__ __launch_bounds__(256) void scalev_kernel(
    u16* __restrict__ Vthi, u16* __restrict__ Vtlo, const float* __restrict__ rinv)
{
  size_t t = (size_t)blockIdx.x*256 + threadIdx.x;   // 262144 threads
  size_t base = t*8;
  int bc = (int)(base >> 12);          // b*CH + c
  int b  = bc >> 7;
  int j0 = (int)(base & (NP-1));
  us8 h = *(const us8*)&Vthi[base];
  us8 l = *(const us8*)&Vtlo[base];
  f32x4 r0 = *(const f32x4*)&rinv[((size_t)b<<12) + j0];
  f32x4 r1 = *(const f32x4*)&rinv[((size_t)b<<12) + j0 + 4];
  us8 oh, ol;
  #pragma unroll
  for (int e=0;e<8;++e){
    float v = (bf2f(h[e]) + bf2f(l[e])) * (e<4 ? r0[e] : r1[e-4]);
    u16 hb = f2bf(v);
    oh[e] = hb;
    ol[e] = f2bf(v - bf2f(hb));
  }
  *(us8*)&Vthi[base] = oh;
  *(us8*)&Vtlo[base] = ol;
}

// ---------------------------------------------------------------------------
// Kernel 4: block-tiled flash. Block = 128 i rows x 1024 j (jsplit of 4).
// xacc[b][c][i] += sum_j exp(S[i][j]) V'[j][c]   (fp32 atomics, xacc zeroed)
// ---------------------------------------------------------------------------
__global__ __launch_bounds__(256,2) void attn_kernel(
    const u16* __restrict__ Qhi, const u16* __restrict__ Qlo,
    const u16* __restrict__ Khi, const u16* __restrict__ Klo,
    const u16* __restrict__ Vthi, const u16* __restrict__ Vtlo,
    float* __restrict__ xacc)
{
  __shared__ u16 Ksh[32*KPAD], Ksl[32*KPAD];
  __shared__ u16 Vsh[CH*VPAD], Vsl[CH*VPAD];
  __shared__ u16 Psh[4][32*PPAD], Psl[4][32*PPAD];
  const int b = blockIdx.z, jsplit = blockIdx.y;
  const int tid = threadIdx.x, lane = tid&63, w = tid>>6;
  const int l15 = lane&15, quad = lane>>4;
  const int i0 = blockIdx.x*128 + w*32;

  bf16x8 qh[2][4], ql[2][4];
  #pragma unroll
  for (int mt=0;mt<2;++mt)
    #pragma unroll
    for (int s=0;s<4;++s){
      size_t g = ((size_t)b*NP + i0 + mt*16 + l15)*CH + s*32 + quad*8;
      qh[mt][s] = ld8(&Qhi[g]); ql[mt][s] = ld8(&Qlo[g]);
    }
  f32x4 acc[2][8];
  #pragma unroll
  for (int mt=0;mt<2;++mt)
    #pragma unroll
    for (int ct=0;ct<8;++ct) acc[mt][ct] = (f32x4){0.f,0.f,0.f,0.f};

  for (int jt=0; jt<32; ++jt){
    const int j0 = jsplit*1024 + jt*32;
    // stage K (32x128) and V' (128x32), hi+lo: 8 rounds of 256x16B
    #pragma unroll
    for (int r=0;r<2;++r){
      int id = tid + r*256, row = id>>4, c16 = id&15;
      size_t g = ((size_t)b*NP + j0 + row)*CH + c16*8;
      *(us8*)&Ksh[row*KPAD + c16*8] = *(const us8*)&Khi[g];
      *(us8*)&Ksl[row*KPAD + c16*8] = *(const us8*)&Klo[g];
    }
    #pragma unroll
    for (int r=0;r<2;++r){
      int id = tid + r*256, row = id>>2, c4 = id&3;
      size_t g = ((size_t)b*CH + row)*NP + j0 + c4*8;
      *(us8*)&Vsh[row*VPAD + c4*8] = *(const us8*)&Vthi[g];
      *(us8*)&Vsl[row*VPAD + c4*8] = *(const us8*)&Vtlo[g];
    }
    __syncthreads();
    // S tiles -> P (exp, hi/lo split) into per-wave scratch
    #pragma unroll
    for (int mt=0;mt<2;++mt){
      #pragma unroll
      for (int js=0;js<2;++js){
        f32x4 s4 = {0.f,0.f,0.f,0.f};
        #pragma unroll
        for (int s=0;s<4;++s){
          int o = (js*16+l15)*KPAD + s*32 + quad*8;
          bf16x8 kbh = ld8(&Ksh[o]);
          bf16x8 kbl = ld8(&Ksl[o]);
          s4 = mfma16(qh[mt][s], kbl, s4);
          s4 = mfma16(ql[mt][s], kbh, s4);
          s4 = mfma16(qh[mt][s], kbh, s4);
        }
        #pragma unroll
        for (int r=0;r<4;++r){
          float p = __expf(s4[r]);
          u16 hb = f2bf(p);
          int row = mt*16 + quad*4 + r;
          Psh[w][row*PPAD + js*16 + l15] = hb;
          Psl[w][row*PPAD + js*16 + l15] = f2bf(p - bf2f(hb));
        }
      }
    }
    __asm__ volatile("s_waitcnt lgkmcnt(0)" ::: "memory");  // wave-local P RAW
    bf16x8 pah[2], pal[2];
    #pragma unroll
    for (int mt=0;mt<2;++mt){
      pah[mt] = ld8(&Psh[w][(mt*16+l15)*PPAD + quad*8]);
      pal[mt] = ld8(&Psl[w][(mt*16+l15)*PPAD + quad*8]);
    }
    #pragma unroll
    for (int ct=0;ct<8;++ct){
      int o = (ct*16+l15)*VPAD + quad*8;
      bf16x8 vbh = ld8(&Vsh[o]);
      bf16x8 vbl = ld8(&Vsl[o]);
      #pragma unroll
      for (int mt=0;mt<2;++mt){
        acc[mt][ct] = mfma16(pah[mt], vbl, acc[mt][ct]);
        acc[mt][ct] = mfma16(pal[mt], vbh, acc[mt][ct]);
        acc[mt][ct] = mfma16(pah[mt], vbh, acc[mt][ct]);
      }
    }
    __syncthreads();
  }
  float* xp = xacc + (size_t)b*CH*NP;
  #pragma unroll
  for (int mt=0;mt<2;++mt){
    #pragma unroll
    for (int ct=0;ct<8;++ct){
      int c = ct*16 + l15;
      int i = i0 + mt*16 + quad*4;
      float* p = &xp[(size_t)c*NP + i];
      #pragma unroll
      for (int e=0;e<4;++e) atomicAdd(p+e, acc[mt][ct][e]);
    }
  }
}

// ---------------------------------------------------------------------------
// Kernel 5: out = X + xacc
// ---------------------------------------------------------------------------
__global__ __launch_bounds__(256) void final_kernel(
    const float* __restrict__ X, const float* __restrict__ xacc,
    float* __restrict__ out)
{
  size_t idx = ((size_t)blockIdx.x*256 + threadIdx.x)*4;
  f32x4 x = *(const f32x4*)&X[idx];
  f32x4 a = *(const f32x4*)&xacc[idx];
  f32x4 r;
  #pragma unroll
  for (int e=0;e<4;++e) r[e] = x[e] + a[e];
  *(f32x4*)&out[idx] = r;
}

extern "C" void kernel_launch(void* const* d_in, const int* in_sizes, int n_in,
                              void* d_out, int out_size, void* d_ws, size_t ws_size,
                              hipStream_t stream)
{
  const float* X  = (const float*)d_in[0];
  const float* Wq = (const float*)d_in[1];
  const float* bq = (const float*)d_in[2];
  const float* Wk = (const float*)d_in[3];
  const float* bk = (const float*)d_in[4];
  const float* Wv = (const float*)d_in[5];
  const float* bv = (const float*)d_in[6];
  float* outp = (float*)d_out;

  const size_t n = (size_t)NB*NP*CH;        // 2,097,152
  u16* Qhi = (u16*)d_ws;
  u16* Qlo = Qhi + n;
  u16* Khi = Qlo + n;
  u16* Klo = Khi + n;
  u16* Vthi = Klo + n;
  u16* Vtlo = Vthi + n;
  u16* Whi  = Vtlo + n;                     // 3*16384
  u16* Wlo  = Whi + 3*CH*CH;
  float* colpart = (float*)(Wlo + 3*CH*CH); // 4*NB*NP
  float* rinv    = colpart + 4*(size_t)NB*NP;
  float* xacc    = rinv + (size_t)NB*NP;    // NB*CH*NP fp32 = 8 MB

  hipMemsetAsync(xacc, 0, n*sizeof(float), stream);

  wsplit_kernel<<<dim3(CH*CH/256, 3),        256, 0, stream>>>(Wq, Wk, Wv, Whi, Wlo);
  proj_kernel  <<<dim3(NP/16, NB),            64, 0, stream>>>(X, Whi, Wlo, bq, bk, bv,
                                                               Qhi,Qlo, Khi,Klo, Vthi,Vtlo);
  stats_kernel <<<dim3(NP/64, 4, NB),        256, 0, stream>>>(Qhi,Qlo, Khi,Klo, colpart);
  rinv_kernel  <<<dim3(NB*NP/256),           256, 0, stream>>>(colpart, rinv);
  scalev_kernel<<<dim3(n/(256*8)),           256, 0, stream>>>(Vthi, Vtlo, rinv);
  attn_kernel  <<<dim3(NP/128, 4, NB),       256, 0, stream>>>(Qhi,Qlo, Khi,Klo,
                                                               Vthi,Vtlo, xacc);
  final_kernel <<<dim3(n/(256*4)),           256, 0, stream>>>(X, xacc, outp);
}

// Round 4
// 343.865 us; speedup vs baseline: 2.4079x; 1.1593x over previous
//
#include <hip/hip_runtime.h>
#include <hip/hip_bf16.h>

// SelfAttention (B=4, C=128, H=W=64), fp32 I/O.
// out[b,c,i] = X[b,c,i] + sum_j exp(S[i,j]) * rinv_j * V[j,c],
//   S = Q K^T, rinv_j = 1/sum_i exp(S[i,j])   (softmax over query axis)
// fp32-faithful via split-bf16 (hi+lo) 3-term MFMA emulation, 32x32x16 MFMA.

typedef unsigned short u16;
typedef __attribute__((ext_vector_type(8))) __bf16 bf16x8;
typedef __attribute__((ext_vector_type(8))) unsigned short us8;
typedef __attribute__((ext_vector_type(4))) float f32x4;
typedef __attribute__((ext_vector_type(16))) float f32x16;

#define NB 4
#define CH 128
#define NP 4096

__device__ __forceinline__ float bf2f(u16 b){ union{float f;unsigned u;}v; v.u=((unsigned)b)<<16; return v.f; }
__device__ __forceinline__ u16 f2bf(float f){ union{float f;unsigned u;}v; v.f=f; unsigned r=v.u + 0x7FFFu + ((v.u>>16)&1u); return (u16)(r>>16); }

__device__ __forceinline__ f32x4 mfma16(bf16x8 a, bf16x8 b, f32x4 c){
  return __builtin_amdgcn_mfma_f32_16x16x32_bf16(a, b, c, 0, 0, 0);
}
__device__ __forceinline__ f32x16 mfma32(bf16x8 a, bf16x8 b, f32x16 c){
  return __builtin_amdgcn_mfma_f32_32x32x16_bf16(a, b, c, 0, 0, 0);
}
__device__ __forceinline__ bf16x8 ld8(const u16* p){
  union { us8 u; bf16x8 b; } v; v.u = *(const us8*)p; return v.b;
}
__device__ __forceinline__ void split8(const float* p, bf16x8& h, bf16x8& l){
  union { us8 u; bf16x8 b; } uh, ul;
  #pragma unroll
  for (int e=0;e<8;++e){
    float f = p[e];
    u16 hb = f2bf(f);
    uh.u[e] = hb;
    ul.u[e] = f2bf(f - bf2f(hb));
  }
  h = uh.b; l = ul.b;
}
// pack (a,b) -> bf16 pair dword (hi) + residual bf16 pair dword (lo), RNE
__device__ __forceinline__ void pksplit(float a, float b, unsigned& dhi, unsigned& dlo){
  float2 f2; f2.x = a; f2.y = b;
  __hip_bfloat162 hb = __float22bfloat162_rn(f2);
  unsigned u; __builtin_memcpy(&u, &hb, 4);
  dhi = u;
  union{unsigned x;float f;} ca, cb;
  ca.x = u << 16; cb.x = u & 0xFFFF0000u;
  float2 g2; g2.x = a - ca.f; g2.y = b - cb.f;
  __hip_bfloat162 lb = __float22bfloat162_rn(g2);
  __builtin_memcpy(&dlo, &lb, 4);
}
__device__ __forceinline__ void gll16(const void* g, void* l){
  __builtin_amdgcn_global_load_lds((const __attribute__((address_space(1))) void*)g,
                                   (__attribute__((address_space(3))) void*)l, 16, 0, 0);
}

// ---------------------------------------------------------------------------
// Kernel 0: pre-split the three 128x128 weight matrices into bf16 hi/lo.
// ---------------------------------------------------------------------------
__global__ __launch_bounds__(256) void wsplit_kernel(
    const float* __restrict__ Wq, const float* __restrict__ Wk,
    const float* __restrict__ Wv, u16* __restrict__ Whi, u16* __restrict__ Wlo)
{
  const int m = blockIdx.y;
  const float* W = (m==0) ? Wq : (m==1) ? Wk : Wv;
  int i = blockIdx.x*256 + threadIdx.x;
  float f = W[i];
  u16 hb = f2bf(f);
  Whi[m*CH*CH + i] = hb;
  Wlo[m*CH*CH + i] = f2bf(f - bf2f(hb));
}

// ---------------------------------------------------------------------------
// Kernel 1: projections (one wave per 16-pixel tile), 16x16x32 MFMA.
// Q/K stored [b][i][ch] hi/lo; V stored transposed [b][c][j] hi/lo.
// ---------------------------------------------------------------------------
__global__ __launch_bounds__(64) void proj_kernel(
    const float* __restrict__ X,
    const u16* __restrict__ Whi, const u16* __restrict__ Wlo,
    const float* __restrict__ bq, const float* __restrict__ bk,
    const float* __restrict__ bv,
    u16* __restrict__ Qhi, u16* __restrict__ Qlo,
    u16* __restrict__ Khi, u16* __restrict__ Klo,
    u16* __restrict__ Vthi, u16* __restrict__ Vtlo)
{
  __shared__ float XT[16][CH+4];
  const int b = blockIdx.y, p0 = blockIdx.x*16, lane = threadIdx.x;
  #pragma unroll
  for (int h=0; h<2; ++h){
    int c = lane + h*64;
    const float* src = X + ((size_t)b*CH + c)*NP + p0;
    #pragma unroll
    for (int v4=0; v4<4; ++v4){
      f32x4 v = *(const f32x4*)(src + v4*4);
      #pragma unroll
      for (int p=0;p<4;++p) XT[v4*4+p][c] = v[p];
    }
  }
  __syncthreads();
  const int l15 = lane&15, quad = lane>>4;
  bf16x8 xh[4], xl[4];
  #pragma unroll
  for (int s=0;s<4;++s) split8(&XT[l15][s*32+quad*8], xh[s], xl[s]);

  const float* bm[2] = {bq, bk};
  u16* OH[2] = {Qhi, Khi};
  u16* OL[2] = {Qlo, Klo};
  #pragma unroll
  for (int m=0;m<2;++m){
    const u16* WH = Whi + m*CH*CH;
    const u16* WL = Wlo + m*CH*CH;
    #pragma unroll
    for (int nt=0;nt<8;++nt){
      f32x4 a = {0.f,0.f,0.f,0.f};
      #pragma unroll
      for (int s=0;s<4;++s){
        size_t g = (size_t)(nt*16+l15)*CH + s*32 + quad*8;
        bf16x8 wh = ld8(&WH[g]), wl = ld8(&WL[g]);
        a = mfma16(xh[s], wl, a);
        a = mfma16(xl[s], wh, a);
        a = mfma16(xh[s], wh, a);
      }
      int o = nt*16 + l15;
      float bias = bm[m][o];
      #pragma unroll
      for (int r=0;r<4;++r){
        int i = p0 + quad*4 + r;
        float q = a[r] + bias;
        u16 hb = f2bf(q);
        size_t idx = ((size_t)b*NP + i)*CH + o;
        OH[m][idx] = hb;
        OL[m][idx] = f2bf(q - bf2f(hb));
      }
    }
  }
  const u16* WH = Whi + 2*CH*CH;
  const u16* WL = Wlo + 2*CH*CH;
  #pragma unroll
  for (int mt=0;mt<8;++mt){
    f32x4 a = {0.f,0.f,0.f,0.f};
    #pragma unroll
    for (int s=0;s<4;++s){
      size_t g = (size_t)(mt*16+l15)*CH + s*32 + quad*8;
      bf16x8 wh = ld8(&WH[g]), wl = ld8(&WL[g]);
      a = mfma16(wh, xl[s], a);
      a = mfma16(wl, xh[s], a);
      a = mfma16(wh, xh[s], a);
    }
    #pragma unroll
    for (int r=0;r<4;++r){
      int co = mt*16 + quad*4 + r;
      float v = a[r] + bv[co];
      u16 hb = f2bf(v);
      size_t idx = ((size_t)b*CH + co)*NP + p0 + l15;
      Vthi[idx] = hb;
      Vtlo[idx] = f2bf(v - bf2f(hb));
    }
  }
}

// ---------------------------------------------------------------------------
// Kernel 2: partial column sums via S^T = K Q^T with 32x32x16 MFMA.
// Wave owns 32 j (K frags register-resident), streams 1024 i in 32-chunks.
// colpart[isplit][b][j] = sum_{i in chunk} exp(S[i][j])
// ---------------------------------------------------------------------------
__global__ __launch_bounds__(256,2) void stats_kernel(
    const u16* __restrict__ Qhi, const u16* __restrict__ Qlo,
    const u16* __restrict__ Khi, const u16* __restrict__ Klo,
    float* __restrict__ colpart)
{
  const int b = blockIdx.z, isplit = blockIdx.y;
  const int tid = threadIdx.x, lane = tid&63, w = tid>>6;
  const int l31 = lane&31, h = lane>>5;
  const int j0w = blockIdx.x*128 + w*32;

  bf16x8 kh[8], kl[8];
  #pragma unroll
  for (int ks=0;ks<8;++ks){
    size_t g = ((size_t)b*NP + j0w + l31)*CH + ks*16 + h*8;
    kh[ks] = ld8(&Khi[g]);
    kl[ks] = ld8(&Klo[g]);
  }
  float scol[16];
  #pragma unroll
  for (int r=0;r<16;++r) scol[r] = 0.f;

  for (int ic=0; ic<32; ++ic){
    int i0 = isplit*1024 + ic*32;
    bf16x8 qh[8], ql[8];
    #pragma unroll
    for (int ks=0;ks<8;++ks){
      size_t g = ((size_t)b*NP + i0 + l31)*CH + ks*16 + h*8;
      qh[ks] = ld8(&Qhi[g]); ql[ks] = ld8(&Qlo[g]);
    }
    f32x16 s;
    #pragma unroll
    for (int r=0;r<16;++r) s[r] = 0.f;
    #pragma unroll
    for (int ks=0;ks<8;++ks){
      s = mfma32(kh[ks], ql[ks], s);
      s = mfma32(kl[ks], qh[ks], s);
      s = mfma32(kh[ks], qh[ks], s);
    }
    #pragma unroll
    for (int r=0;r<16;++r) scol[r] += __expf(s[r]);
  }
  // reduce over the 32 i-lanes (same h keeps same j)
  #pragma unroll
  for (int m=1; m<32; m<<=1){
    #pragma unroll
    for (int r=0;r<16;++r) scol[r] += __shfl_xor(scol[r], m);
  }
  if (l31 == 0){
    #pragma unroll
    for (int r=0;r<16;++r){
      int j = j0w + (r&3) + 8*(r>>2) + 4*h;
      colpart[((size_t)(isplit*NB + b))*NP + j] = scol[r];
    }
  }
}

// ---------------------------------------------------------------------------
// Kernel 3a: rinv[b][j] = 1 / sum_isplit colpart
// ---------------------------------------------------------------------------
__global__ __launch_bounds__(256) void rinv_kernel(
    const float* __restrict__ colpart, float* __restrict__ rinv)
{
  int idx = blockIdx.x*256 + threadIdx.x;        // NB*NP = 16384
  int b = idx >> 12, j = idx & (NP-1);
  float s = 0.f;
  #pragma unroll
  for (int k=0;k<4;++k) s += colpart[((size_t)(k*NB + b))*NP + j];
  rinv[idx] = 1.0f / s;
}

// ---------------------------------------------------------------------------
// Kernel 3b: in-place V' = rinv_j * V   (hi/lo re-split)
// ---------------------------------------------------------------------------
__global__ __launch_bounds__(256) void scalev_kernel(
    u16* __restrict__ Vthi, u16* __restrict__ Vtlo, const float* __restrict__ rinv)
{
  size_t t = (size_t)blockIdx.x*256 + threadIdx.x;
  size_t base = t*8;
  int bc = (int)(base >> 12);
  int b  = bc >> 7;
  int j0 = (int)(base & (NP-1));
  us8 h = *(const us8*)&Vthi[base];
  us8 l = *(const us8*)&Vtlo[base];
  f32x4 r0 = *(const f32x4*)&rinv[((size_t)b<<12) + j0];
  f32x4 r1 = *(const f32x4*)&rinv[((size_t)b<<12) + j0 + 4];
  us8 oh, ol;
  #pragma unroll
  for (int e=0;e<8;++e){
    float v = (bf2f(h[e]) + bf2f(l[e])) * (e<4 ? r0[e] : r1[e-4]);
    u16 hb = f2bf(v);
    oh[e] = hb;
    ol[e] = f2bf(v - bf2f(hb));
  }
  *(us8*)&Vthi[base] = oh;
  *(us8*)&Vtlo[base] = ol;
}

// ---------------------------------------------------------------------------
// Kernel 4: flash attn, 32x32x16, S^T formulation, in-register P transpose,
// global_load_lds double-buffered staging, one barrier per j-tile.
// LDS layout [chunk16B][row] (unpadded, bank-clean).
// ---------------------------------------------------------------------------
__global__ __launch_bounds__(256,2) void attn_kernel(
    const u16* __restrict__ Qhi, const u16* __restrict__ Qlo,
    const u16* __restrict__ Khi, const u16* __restrict__ Klo,
    const u16* __restrict__ Vthi, const u16* __restrict__ Vtlo,
    float* __restrict__ xacc)
{
  __shared__ u16 SK[2][2][32*CH];    // [buf][hi/lo][chunk(c16)*32 + row] * 8 elems
  __shared__ u16 SV[2][2][4*CH*8];   // [buf][hi/lo][chunk(c4)*128 + row] * 8 elems
  const int b = blockIdx.z, jsplit = blockIdx.y;
  const int tid = threadIdx.x, lane = tid&63, w = tid>>6;
  const int l31 = lane&31, h = lane>>5;
  const int i0w = blockIdx.x*128 + w*32;
  const bool hb1 = (h != 0);

  // per-lane staging coordinates (2 GLL instrs per array per wave)
  int slot0 = (w*2+0)*64 + lane, slot1 = (w*2+1)*64 + lane;
  const int kr0 = slot0&31, kc0 = slot0>>5, kr1 = slot1&31, kc1 = slot1>>5;
  const int vr0 = slot0&127, vc0 = slot0>>7, vr1 = slot1&127, vc1 = slot1>>7;
  const size_t kg0 = ((size_t)b*NP + kr0)*CH + kc0*8;
  const size_t kg1 = ((size_t)b*NP + kr1)*CH + kc1*8;
  const size_t vg0 = ((size_t)b*CH + vr0)*NP + vc0*8;
  const size_t vg1 = ((size_t)b*CH + vr1)*NP + vc1*8;
  const int lof0 = slot0*8, lof1 = slot1*8;

  // Q B-fragments resident: B[k=ks*16+h*8+e][n=i=l31]
  bf16x8 qh[8], ql[8];
  #pragma unroll
  for (int ks=0;ks<8;++ks){
    size_t g = ((size_t)b*NP + i0w + l31)*CH + ks*16 + h*8;
    qh[ks] = ld8(&Qhi[g]); ql[ks] = ld8(&Qlo[g]);
  }
  f32x16 acc[4];
  #pragma unroll
  for (int mt=0;mt<4;++mt)
    #pragma unroll
    for (int r=0;r<16;++r) acc[mt][r] = 0.f;

  const int jbase = jsplit*1024;
  // stage tile 0 into buf 0
  {
    int j0 = jbase;
    gll16(&Khi[kg0 + (size_t)j0*CH], &SK[0][0][lof0]);
    gll16(&Khi[kg1 + (size_t)j0*CH], &SK[0][0][lof1]);
    gll16(&Klo[kg0 + (size_t)j0*CH], &SK[0][1][lof0]);
    gll16(&Klo[kg1 + (size_t)j0*CH], &SK[0][1][lof1]);
    gll16(&Vthi[vg0 + j0], &SV[0][0][lof0]);
    gll16(&Vthi[vg1 + j0], &SV[0][0][lof1]);
    gll16(&Vtlo[vg0 + j0], &SV[0][1][lof0]);
    gll16(&Vtlo[vg1 + j0], &SV[0][1][lof1]);
  }
  __syncthreads();

  for (int jt=0; jt<32; ++jt){
    if (jt < 31){
      int nb = (jt+1)&1, j0 = jbase + (jt+1)*32;
      gll16(&Khi[kg0 + (size_t)j0*CH], &SK[nb][0][lof0]);
      gll16(&Khi[kg1 + (size_t)j0*CH], &SK[nb][0][lof1]);
      gll16(&Klo[kg0 + (size_t)j0*CH], &SK[nb][1][lof0]);
      gll16(&Klo[kg1 + (size_t)j0*CH], &SK[nb][1][lof1]);
      gll16(&Vthi[vg0 + j0], &SV[nb][0][lof0]);
      gll16(&Vthi[vg1 + j0], &SV[nb][0][lof1]);
      gll16(&Vtlo[vg0 + j0], &SV[nb][1][lof0]);
      gll16(&Vtlo[vg1 + j0], &SV[nb][1][lof1]);
    }
    const int cb = jt&1;
    const u16* Kh = &SK[cb][0][0];
    const u16* Kl = &SK[cb][1][0];
    const u16* Vh = &SV[cb][0][0];
    const u16* Vl = &SV[cb][1][0];

    // S^T tile: A=K[m=j=l31][k], B=Q  -> C/D: col=i=l31, row=j
    f32x16 s;
    #pragma unroll
    for (int r=0;r<16;++r) s[r] = 0.f;
    #pragma unroll
    for (int ks=0;ks<8;++ks){
      int o = (ks*2+h)*256 + l31*8;          // chunk (ks*2+h), row l31
      bf16x8 ah = ld8(&Kh[o]);
      bf16x8 al = ld8(&Kl[o]);
      s = mfma32(ah, ql[ks], s);
      s = mfma32(al, qh[ks], s);
      s = mfma32(ah, qh[ks], s);
    }
    float p[16];
    #pragma unroll
    for (int r=0;r<16;++r) p[r] = __expf(s[r]);

    // two k-tiles of 16 j each: assemble P^T B-frags in-register
    #pragma unroll
    for (int t=0;t<2;++t){
      unsigned hA,lA,hB,lB,hC,lC,hD,lD;
      pksplit(p[8*t+0], p[8*t+1], hA, lA);
      pksplit(p[8*t+2], p[8*t+3], hB, lB);
      pksplit(p[8*t+4], p[8*t+5], hC, lC);
      pksplit(p[8*t+6], p[8*t+7], hD, lD);
      unsigned s0h = hb1? hA:hC, s1h = hb1? hB:hD;
      unsigned s0l = hb1? lA:lC, s1l = hb1? lB:lD;
      unsigned r0h = __shfl_xor(s0h, 32), r1h = __shfl_xor(s1h, 32);
      unsigned r0l = __shfl_xor(s0l, 32), r1l = __shfl_xor(s1l, 32);
      unsigned dh[4], dl[4];
      dh[0] = hb1? r0h : hA;  dh[1] = hb1? r1h : hB;
      dh[2] = hb1? hC  : r0h; dh[3] = hb1? hD  : r1h;
      dl[0] = hb1? r0l : lA;  dl[1] = hb1? r1l : lB;
      dl[2] = hb1? lC  : r0l; dl[3] = hb1? lD  : r1l;
      bf16x8 Bh, Bl;
      __builtin_memcpy(&Bh, dh, 16);
      __builtin_memcpy(&Bl, dl, 16);
      // PV: A = V'^T[m=c][k=j], B = P^T -> acc[c][i]
      #pragma unroll
      for (int mt=0;mt<4;++mt){
        int o = (t*2+h)*1024 + (mt*32+l31)*8;  // chunk (t*2+h), row c
        bf16x8 vh = ld8(&Vh[o]);
        bf16x8 vl = ld8(&Vl[o]);
        acc[mt] = mfma32(vh, Bl, acc[mt]);
        acc[mt] = mfma32(vl, Bh, acc[mt]);
        acc[mt] = mfma32(vh, Bh, acc[mt]);
      }
    }
    __syncthreads();
  }
  // epilogue: acc[mt][r] = O^T[c][i], c = mt*32 + (r&3)+8*(r>>2)+4*h, i = i0w+l31
  float* xp = xacc + (size_t)b*CH*NP;
  #pragma unroll
  for (int mt=0;mt<4;++mt){
    #pragma unroll
    for (int r=0;r<16;++r){
      int c = mt*32 + (r&3) + 8*(r>>2) + 4*h;
      atomicAdd(&xp[(size_t)c*NP + i0w + l31], acc[mt][r]);
    }
  }
}

// ---------------------------------------------------------------------------
// Kernel 5: out = X + xacc
// ---------------------------------------------------------------------------
__global__ __launch_bounds__(256) void final_kernel(
    const float* __restrict__ X, const float* __restrict__ xacc,
    float* __restrict__ out)
{
  size_t idx = ((size_t)blockIdx.x*256 + threadIdx.x)*4;
  f32x4 x = *(const f32x4*)&X[idx];
  f32x4 a = *(const f32x4*)&xacc[idx];
  f32x4 r;
  #pragma unroll
  for (int e=0;e<4;++e) r[e] = x[e] + a[e];
  *(f32x4*)&out[idx] = r;
}

extern "C" void kernel_launch(void* const* d_in, const int* in_sizes, int n_in,
                              void* d_out, int out_size, void* d_ws, size_t ws_size,
                              hipStream_t stream)
{
  const float* X  = (const float*)d_in[0];
  const float* Wq = (const float*)d_in[1];
  const float* bq = (const float*)d_in[2];
  const float* Wk = (const float*)d_in[3];
  const float* bk = (const float*)d_in[4];
  const float* Wv = (const float*)d_in[5];
  const float* bv = (const float*)d_in[6];
  float* outp = (float*)d_out;

  const size_t n = (size_t)NB*NP*CH;        // 2,097,152
  u16* Qhi = (u16*)d_ws;
  u16* Qlo = Qhi + n;
  u16* Khi = Qlo + n;
  u16* Klo = Khi + n;
  u16* Vthi = Klo + n;
  u16* Vtlo = Vthi + n;
  u16* Whi  = Vtlo + n;
  u16* Wlo  = Whi + 3*CH*CH;
  float* colpart = (float*)(Wlo + 3*CH*CH); // 4*NB*NP
  float* rinv    = colpart + 4*(size_t)NB*NP;
  float* xacc    = rinv + (size_t)NB*NP;    // NB*CH*NP fp32 = 8 MB

  hipMemsetAsync(xacc, 0, n*sizeof(float), stream);

  wsplit_kernel<<<dim3(CH*CH/256, 3),   256, 0, stream>>>(Wq, Wk, Wv, Whi, Wlo);
  proj_kernel  <<<dim3(NP/16, NB),       64, 0, stream>>>(X, Whi, Wlo, bq, bk, bv,
                                                          Qhi,Qlo, Khi,Klo, Vthi,Vtlo);
  stats_kernel <<<dim3(NP/128, 4, NB),  256, 0, stream>>>(Qhi,Qlo, Khi,Klo, colpart);
  rinv_kernel  <<<dim3(NB*NP/256),      256, 0, stream>>>(colpart, rinv);
  scalev_kernel<<<dim3(n/(256*8)),      256, 0, stream>>>(Vthi, Vtlo, rinv);
  attn_kernel  <<<dim3(NP/128, 4, NB),  256, 0, stream>>>(Qhi,Qlo, Khi,Klo,
                                                          Vthi,Vtlo, xacc);
  final_kernel <<<dim3(n/(256*4)),      256, 0, stream>>>(X, xacc, outp);
}

// Round 5
// 276.255 us; speedup vs baseline: 2.9972x; 1.2447x over previous
//
#include <hip/hip_runtime.h>
#include <hip/hip_bf16.h>

// SelfAttention (B=4, C=128, H=W=64), fp32 I/O.
// out[b,c,i] = X[b,c,i] + sum_j exp(S[i,j]) * rinv_j * V[j,c],
//   S = Q K^T, rinv_j = 1/sum_i exp(S[i,j])   (softmax over query axis)
// fp32-faithful via split-bf16 (hi+lo) 3-term MFMA emulation, 32x32x16 MFMA.

typedef unsigned short u16;
typedef __attribute__((ext_vector_type(8))) __bf16 bf16x8;
typedef __attribute__((ext_vector_type(8))) unsigned short us8;
typedef __attribute__((ext_vector_type(4))) float f32x4;
typedef __attribute__((ext_vector_type(16))) float f32x16;

#define NB 4
#define CH 128
#define NP 4096

__device__ __forceinline__ float bf2f(u16 b){ union{float f;unsigned u;}v; v.u=((unsigned)b)<<16; return v.f; }
__device__ __forceinline__ u16 f2bf(float f){ union{float f;unsigned u;}v; v.f=f; unsigned r=v.u + 0x7FFFu + ((v.u>>16)&1u); return (u16)(r>>16); }

__device__ __forceinline__ f32x4 mfma16(bf16x8 a, bf16x8 b, f32x4 c){
  return __builtin_amdgcn_mfma_f32_16x16x32_bf16(a, b, c, 0, 0, 0);
}
__device__ __forceinline__ f32x16 mfma32(bf16x8 a, bf16x8 b, f32x16 c){
  return __builtin_amdgcn_mfma_f32_32x32x16_bf16(a, b, c, 0, 0, 0);
}
__device__ __forceinline__ bf16x8 ld8(const u16* p){
  union { us8 u; bf16x8 b; } v; v.u = *(const us8*)p; return v.b;
}
__device__ __forceinline__ void split8(const float* p, bf16x8& h, bf16x8& l){
  union { us8 u; bf16x8 b; } uh, ul;
  #pragma unroll
  for (int e=0;e<8;++e){
    float f = p[e];
    u16 hb = f2bf(f);
    uh.u[e] = hb;
    ul.u[e] = f2bf(f - bf2f(hb));
  }
  h = uh.b; l = ul.b;
}
// pack (a,b) -> bf16 pair dword (hi) + residual bf16 pair dword (lo), RNE
__device__ __forceinline__ void pksplit(float a, float b, unsigned& dhi, unsigned& dlo){
  float2 f2; f2.x = a; f2.y = b;
  __hip_bfloat162 hb = __float22bfloat162_rn(f2);
  unsigned u; __builtin_memcpy(&u, &hb, 4);
  dhi = u;
  union{unsigned x;float f;} ca, cb;
  ca.x = u << 16; cb.x = u & 0xFFFF0000u;
  float2 g2; g2.x = a - ca.f; g2.y = b - cb.f;
  __hip_bfloat162 lb = __float22bfloat162_rn(g2);
  __builtin_memcpy(&dlo, &lb, 4);
}
__device__ __forceinline__ void gll16(const void* g, void* l){
  __builtin_amdgcn_global_load_lds((const __attribute__((address_space(1))) void*)g,
                                   (__attribute__((address_space(3))) void*)l, 16, 0, 0);
}

// ---------------------------------------------------------------------------
// Kernel 0: pre-split the three 128x128 weight matrices into bf16 hi/lo.
// ---------------------------------------------------------------------------
__global__ __launch_bounds__(256) void wsplit_kernel(
    const float* __restrict__ Wq, const float* __restrict__ Wk,
    const float* __restrict__ Wv, u16* __restrict__ Whi, u16* __restrict__ Wlo)
{
  const int m = blockIdx.y;
  const float* W = (m==0) ? Wq : (m==1) ? Wk : Wv;
  int i = blockIdx.x*256 + threadIdx.x;
  float f = W[i];
  u16 hb = f2bf(f);
  Whi[m*CH*CH + i] = hb;
  Wlo[m*CH*CH + i] = f2bf(f - bf2f(hb));
}

// ---------------------------------------------------------------------------
// Kernel 1: projections (one wave per 16-pixel tile), 16x16x32 MFMA.
// Q/K stored [b][i][ch] hi/lo; V stored transposed [b][c][j] hi/lo.
// ---------------------------------------------------------------------------
__global__ __launch_bounds__(64) void proj_kernel(
    const float* __restrict__ X,
    const u16* __restrict__ Whi, const u16* __restrict__ Wlo,
    const float* __restrict__ bq, const float* __restrict__ bk,
    const float* __restrict__ bv,
    u16* __restrict__ Qhi, u16* __restrict__ Qlo,
    u16* __restrict__ Khi, u16* __restrict__ Klo,
    u16* __restrict__ Vthi, u16* __restrict__ Vtlo)
{
  __shared__ float XT[16][CH+4];
  const int b = blockIdx.y, p0 = blockIdx.x*16, lane = threadIdx.x;
  #pragma unroll
  for (int h=0; h<2; ++h){
    int c = lane + h*64;
    const float* src = X + ((size_t)b*CH + c)*NP + p0;
    #pragma unroll
    for (int v4=0; v4<4; ++v4){
      f32x4 v = *(const f32x4*)(src + v4*4);
      #pragma unroll
      for (int p=0;p<4;++p) XT[v4*4+p][c] = v[p];
    }
  }
  __syncthreads();
  const int l15 = lane&15, quad = lane>>4;
  bf16x8 xh[4], xl[4];
  #pragma unroll
  for (int s=0;s<4;++s) split8(&XT[l15][s*32+quad*8], xh[s], xl[s]);

  const float* bm[2] = {bq, bk};
  u16* OH[2] = {Qhi, Khi};
  u16* OL[2] = {Qlo, Klo};
  #pragma unroll
  for (int m=0;m<2;++m){
    const u16* WH = Whi + m*CH*CH;
    const u16* WL = Wlo + m*CH*CH;
    #pragma unroll
    for (int nt=0;nt<8;++nt){
      f32x4 a = {0.f,0.f,0.f,0.f};
      #pragma unroll
      for (int s=0;s<4;++s){
        size_t g = (size_t)(nt*16+l15)*CH + s*32 + quad*8;
        bf16x8 wh = ld8(&WH[g]), wl = ld8(&WL[g]);
        a = mfma16(xh[s], wl, a);
        a = mfma16(xl[s], wh, a);
        a = mfma16(xh[s], wh, a);
      }
      int o = nt*16 + l15;
      float bias = bm[m][o];
      #pragma unroll
      for (int r=0;r<4;++r){
        int i = p0 + quad*4 + r;
        float q = a[r] + bias;
        u16 hb = f2bf(q);
        size_t idx = ((size_t)b*NP + i)*CH + o;
        OH[m][idx] = hb;
        OL[m][idx] = f2bf(q - bf2f(hb));
      }
    }
  }
  const u16* WH = Whi + 2*CH*CH;
  const u16* WL = Wlo + 2*CH*CH;
  #pragma unroll
  for (int mt=0;mt<8;++mt){
    f32x4 a = {0.f,0.f,0.f,0.f};
    #pragma unroll
    for (int s=0;s<4;++s){
      size_t g = (size_t)(mt*16+l15)*CH + s*32 + quad*8;
      bf16x8 wh = ld8(&WH[g]), wl = ld8(&WL[g]);
      a = mfma16(wh, xl[s], a);
      a = mfma16(wl, xh[s], a);
      a = mfma16(wh, xh[s], a);
    }
    #pragma unroll
    for (int r=0;r<4;++r){
      int co = mt*16 + quad*4 + r;
      float v = a[r] + bv[co];
      u16 hb = f2bf(v);
      size_t idx = ((size_t)b*CH + co)*NP + p0 + l15;
      Vthi[idx] = hb;
      Vtlo[idx] = f2bf(v - bf2f(hb));
    }
  }
}

// ---------------------------------------------------------------------------
// Kernel 2: partial column sums via S^T = K Q^T with 32x32x16 MFMA.
// Wave owns 32 j (K frags register-resident). Q chunks (32 i) staged in LDS
// via global_load_lds, double-buffered, shared by all 4 waves.
// colpart[isplit][b][j] = sum_{i in chunk} exp(S[i][j])
// ---------------------------------------------------------------------------
__global__ __launch_bounds__(256,3) void stats_kernel(
    const u16* __restrict__ Qhi, const u16* __restrict__ Qlo,
    const u16* __restrict__ Khi, const u16* __restrict__ Klo,
    float* __restrict__ colpart)
{
  __shared__ u16 SQ[2][2][32*CH];   // [buf][hi/lo][chunk(c16)*32 + row] * 8
  const int b = blockIdx.z, isplit = blockIdx.y;
  const int tid = threadIdx.x, lane = tid&63, w = tid>>6;
  const int l31 = lane&31, h = lane>>5;
  const int j0w = blockIdx.x*128 + w*32;

  // staging coords: 512 slots of 16B, 2 per thread
  const int slot0 = w*128 + lane, slot1 = slot0 + 64;
  const int qr0 = slot0&31, qc0 = slot0>>5, qr1 = slot1&31, qc1 = slot1>>5;
  const size_t qg0 = ((size_t)b*NP + qr0)*CH + qc0*8;
  const size_t qg1 = ((size_t)b*NP + qr1)*CH + qc1*8;
  const int lof0 = slot0*8, lof1 = slot1*8;

  // K fragments register-resident: A[m=j=l31][k=ks*16+h*8+e]
  bf16x8 kh[8], kl[8];
  #pragma unroll
  for (int ks=0;ks<8;++ks){
    size_t g = ((size_t)b*NP + j0w + l31)*CH + ks*16 + h*8;
    kh[ks] = ld8(&Khi[g]);
    kl[ks] = ld8(&Klo[g]);
  }

  const int ibase = isplit*1024;
  // stage chunk 0
  gll16(&Qhi[qg0 + (size_t)ibase*CH], &SQ[0][0][lof0]);
  gll16(&Qhi[qg1 + (size_t)ibase*CH], &SQ[0][0][lof1]);
  gll16(&Qlo[qg0 + (size_t)ibase*CH], &SQ[0][1][lof0]);
  gll16(&Qlo[qg1 + (size_t)ibase*CH], &SQ[0][1][lof1]);
  __syncthreads();

  float scol[16];
  #pragma unroll
  for (int r=0;r<16;++r) scol[r] = 0.f;

  for (int ic=0; ic<32; ++ic){
    if (ic < 31){
      int nb = (ic+1)&1;
      size_t iofs = (size_t)(ibase + (ic+1)*32)*CH;
      gll16(&Qhi[qg0 + iofs], &SQ[nb][0][lof0]);
      gll16(&Qhi[qg1 + iofs], &SQ[nb][0][lof1]);
      gll16(&Qlo[qg0 + iofs], &SQ[nb][1][lof0]);
      gll16(&Qlo[qg1 + iofs], &SQ[nb][1][lof1]);
    }
    const int cb = ic&1;
    const u16* Qh = &SQ[cb][0][0];
    const u16* Ql = &SQ[cb][1][0];
    f32x16 s;
    #pragma unroll
    for (int r=0;r<16;++r) s[r] = 0.f;
    #pragma unroll
    for (int ks=0;ks<8;++ks){
      int o = (ks*2+h)*256 + l31*8;      // B[k][n=i=l31]
      bf16x8 qbh = ld8(&Qh[o]);
      bf16x8 qbl = ld8(&Ql[o]);
      s = mfma32(kh[ks], qbl, s);
      s = mfma32(kl[ks], qbh, s);
      s = mfma32(kh[ks], qbh, s);
    }
    #pragma unroll
    for (int r=0;r<16;++r) scol[r] += __expf(s[r]);
    __syncthreads();
  }
  // reduce over the 32 i-lanes (same h keeps same j)
  #pragma unroll
  for (int m=1; m<32; m<<=1){
    #pragma unroll
    for (int r=0;r<16;++r) scol[r] += __shfl_xor(scol[r], m);
  }
  if (l31 == 0){
    #pragma unroll
    for (int r=0;r<16;++r){
      int j = j0w + (r&3) + 8*(r>>2) + 4*h;
      colpart[((size_t)(isplit*NB + b))*NP + j] = scol[r];
    }
  }
}

// ---------------------------------------------------------------------------
// Kernel 3: in-place V' = rinv_j * V (hi/lo re-split), rinv computed inline
// from the 4 colpart partials.
// ---------------------------------------------------------------------------
__global__ __launch_bounds__(256) void scalev_kernel(
    u16* __restrict__ Vthi, u16* __restrict__ Vtlo,
    const float* __restrict__ colpart)
{
  size_t t = (size_t)blockIdx.x*256 + threadIdx.x;
  size_t base = t*8;
  int bc = (int)(base >> 12);
  int b  = bc >> 7;
  int j0 = (int)(base & (NP-1));
  f32x4 s0 = {0.f,0.f,0.f,0.f}, s1 = {0.f,0.f,0.f,0.f};
  #pragma unroll
  for (int k=0;k<4;++k){
    const float* cp = &colpart[((size_t)(k*NB + b))*NP + j0];
    f32x4 a0 = *(const f32x4*)cp;
    f32x4 a1 = *(const f32x4*)(cp+4);
    #pragma unroll
    for (int e=0;e<4;++e){ s0[e]+=a0[e]; s1[e]+=a1[e]; }
  }
  us8 hh = *(const us8*)&Vthi[base];
  us8 ll = *(const us8*)&Vtlo[base];
  us8 oh, ol;
  #pragma unroll
  for (int e=0;e<8;++e){
    float r = 1.0f / (e<4 ? s0[e] : s1[e-4]);
    float v = (bf2f(hh[e]) + bf2f(ll[e])) * r;
    u16 hb = f2bf(v);
    oh[e] = hb;
    ol[e] = f2bf(v - bf2f(hb));
  }
  *(us8*)&Vthi[base] = oh;
  *(us8*)&Vtlo[base] = ol;
}

// ---------------------------------------------------------------------------
// Kernel 4: flash attn, 32x32x16, S^T formulation, in-register P transpose,
// global_load_lds double-buffered staging, one barrier per j-tile.
// ---------------------------------------------------------------------------
__global__ __launch_bounds__(256,2) void attn_kernel(
    const u16* __restrict__ Qhi, const u16* __restrict__ Qlo,
    const u16* __restrict__ Khi, const u16* __restrict__ Klo,
    const u16* __restrict__ Vthi, const u16* __restrict__ Vtlo,
    float* __restrict__ xacc)
{
  __shared__ u16 SK[2][2][32*CH];    // [buf][hi/lo][chunk(c16)*32 + row] * 8
  __shared__ u16 SV[2][2][4*CH*8];   // [buf][hi/lo][chunk(c4)*128 + row] * 8
  const int b = blockIdx.z, jsplit = blockIdx.y;
  const int tid = threadIdx.x, lane = tid&63, w = tid>>6;
  const int l31 = lane&31, h = lane>>5;
  const int i0w = blockIdx.x*128 + w*32;
  const bool hb1 = (h != 0);

  int slot0 = (w*2+0)*64 + lane, slot1 = (w*2+1)*64 + lane;
  const int kr0 = slot0&31, kc0 = slot0>>5, kr1 = slot1&31, kc1 = slot1>>5;
  const int vr0 = slot0&127, vc0 = slot0>>7, vr1 = slot1&127, vc1 = slot1>>7;
  const size_t kg0 = ((size_t)b*NP + kr0)*CH + kc0*8;
  const size_t kg1 = ((size_t)b*NP + kr1)*CH + kc1*8;
  const size_t vg0 = ((size_t)b*CH + vr0)*NP + vc0*8;
  const size_t vg1 = ((size_t)b*CH + vr1)*NP + vc1*8;
  const int lof0 = slot0*8, lof1 = slot1*8;

  bf16x8 qh[8], ql[8];
  #pragma unroll
  for (int ks=0;ks<8;++ks){
    size_t g = ((size_t)b*NP + i0w + l31)*CH + ks*16 + h*8;
    qh[ks] = ld8(&Qhi[g]); ql[ks] = ld8(&Qlo[g]);
  }
  f32x16 acc[4];
  #pragma unroll
  for (int mt=0;mt<4;++mt)
    #pragma unroll
    for (int r=0;r<16;++r) acc[mt][r] = 0.f;

  const int jbase = jsplit*1024;
  {
    int j0 = jbase;
    gll16(&Khi[kg0 + (size_t)j0*CH], &SK[0][0][lof0]);
    gll16(&Khi[kg1 + (size_t)j0*CH], &SK[0][0][lof1]);
    gll16(&Klo[kg0 + (size_t)j0*CH], &SK[0][1][lof0]);
    gll16(&Klo[kg1 + (size_t)j0*CH], &SK[0][1][lof1]);
    gll16(&Vthi[vg0 + j0], &SV[0][0][lof0]);
    gll16(&Vthi[vg1 + j0], &SV[0][0][lof1]);
    gll16(&Vtlo[vg0 + j0], &SV[0][1][lof0]);
    gll16(&Vtlo[vg1 + j0], &SV[0][1][lof1]);
  }
  __syncthreads();

  for (int jt=0; jt<32; ++jt){
    if (jt < 31){
      int nb = (jt+1)&1, j0 = jbase + (jt+1)*32;
      gll16(&Khi[kg0 + (size_t)j0*CH], &SK[nb][0][lof0]);
      gll16(&Khi[kg1 + (size_t)j0*CH], &SK[nb][0][lof1]);
      gll16(&Klo[kg0 + (size_t)j0*CH], &SK[nb][1][lof0]);
      gll16(&Klo[kg1 + (size_t)j0*CH], &SK[nb][1][lof1]);
      gll16(&Vthi[vg0 + j0], &SV[nb][0][lof0]);
      gll16(&Vthi[vg1 + j0], &SV[nb][0][lof1]);
      gll16(&Vtlo[vg0 + j0], &SV[nb][1][lof0]);
      gll16(&Vtlo[vg1 + j0], &SV[nb][1][lof1]);
    }
    const int cb = jt&1;
    const u16* Kh = &SK[cb][0][0];
    const u16* Kl = &SK[cb][1][0];
    const u16* Vh = &SV[cb][0][0];
    const u16* Vl = &SV[cb][1][0];

    f32x16 s;
    #pragma unroll
    for (int r=0;r<16;++r) s[r] = 0.f;
    #pragma unroll
    for (int ks=0;ks<8;++ks){
      int o = (ks*2+h)*256 + l31*8;
      bf16x8 ah = ld8(&Kh[o]);
      bf16x8 al = ld8(&Kl[o]);
      s = mfma32(ah, ql[ks], s);
      s = mfma32(al, qh[ks], s);
      s = mfma32(ah, qh[ks], s);
    }
    float p[16];
    #pragma unroll
    for (int r=0;r<16;++r) p[r] = __expf(s[r]);

    #pragma unroll
    for (int t=0;t<2;++t){
      unsigned hA,lA,hB,lB,hC,lC,hD,lD;
      pksplit(p[8*t+0], p[8*t+1], hA, lA);
      pksplit(p[8*t+2], p[8*t+3], hB, lB);
      pksplit(p[8*t+4], p[8*t+5], hC, lC);
      pksplit(p[8*t+6], p[8*t+7], hD, lD);
      unsigned s0h = hb1? hA:hC, s1h = hb1? hB:hD;
      unsigned s0l = hb1? lA:lC, s1l = hb1? lB:lD;
      unsigned r0h = __shfl_xor(s0h, 32), r1h = __shfl_xor(s1h, 32);
      unsigned r0l = __shfl_xor(s0l, 32), r1l = __shfl_xor(s1l, 32);
      unsigned dh[4], dl[4];
      dh[0] = hb1? r0h : hA;  dh[1] = hb1? r1h : hB;
      dh[2] = hb1? hC  : r0h; dh[3] = hb1? hD  : r1h;
      dl[0] = hb1? r0l : lA;  dl[1] = hb1? r1l : lB;
      dl[2] = hb1? lC  : r0l; dl[3] = hb1? lD  : r1l;
      bf16x8 Bh, Bl;
      __builtin_memcpy(&Bh, dh, 16);
      __builtin_memcpy(&Bl, dl, 16);
      #pragma unroll
      for (int mt=0;mt<4;++mt){
        int o = (t*2+h)*1024 + (mt*32+l31)*8;
        bf16x8 vh = ld8(&Vh[o]);
        bf16x8 vl = ld8(&Vl[o]);
        acc[mt] = mfma32(vh, Bl, acc[mt]);
        acc[mt] = mfma32(vl, Bh, acc[mt]);
        acc[mt] = mfma32(vh, Bh, acc[mt]);
      }
    }
    __syncthreads();
  }
  float* xp = xacc + (size_t)b*CH*NP;
  #pragma unroll
  for (int mt=0;mt<4;++mt){
    #pragma unroll
    for (int r=0;r<16;++r){
      int c = mt*32 + (r&3) + 8*(r>>2) + 4*h;
      atomicAdd(&xp[(size_t)c*NP + i0w + l31], acc[mt][r]);
    }
  }
}

// ---------------------------------------------------------------------------
// Kernel 5: out = X + xacc
// ---------------------------------------------------------------------------
__global__ __launch_bounds__(256) void final_kernel(
    const float* __restrict__ X, const float* __restrict__ xacc,
    float* __restrict__ out)
{
  size_t idx = ((size_t)blockIdx.x*256 + threadIdx.x)*4;
  f32x4 x = *(const f32x4*)&X[idx];
  f32x4 a = *(const f32x4*)&xacc[idx];
  f32x4 r;
  #pragma unroll
  for (int e=0;e<4;++e) r[e] = x[e] + a[e];
  *(f32x4*)&out[idx] = r;
}

extern "C" void kernel_launch(void* const* d_in, const int* in_sizes, int n_in,
                              void* d_out, int out_size, void* d_ws, size_t ws_size,
                              hipStream_t stream)
{
  const float* X  = (const float*)d_in[0];
  const float* Wq = (const float*)d_in[1];
  const float* bq = (const float*)d_in[2];
  const float* Wk = (const float*)d_in[3];
  const float* bk = (const float*)d_in[4];
  const float* Wv = (const float*)d_in[5];
  const float* bv = (const float*)d_in[6];
  float* outp = (float*)d_out;

  const size_t n = (size_t)NB*NP*CH;        // 2,097,152
  u16* Qhi = (u16*)d_ws;
  u16* Qlo = Qhi + n;
  u16* Khi = Qlo + n;
  u16* Klo = Khi + n;
  u16* Vthi = Klo + n;
  u16* Vtlo = Vthi + n;
  u16* Whi  = Vtlo + n;
  u16* Wlo  = Whi + 3*CH*CH;
  float* colpart = (float*)(Wlo + 3*CH*CH); // 4*NB*NP
  float* xacc    = colpart + 4*(size_t)NB*NP;   // NB*CH*NP fp32 = 8 MB

  hipMemsetAsync(xacc, 0, n*sizeof(float), stream);

  wsplit_kernel<<<dim3(CH*CH/256, 3),   256, 0, stream>>>(Wq, Wk, Wv, Whi, Wlo);
  proj_kernel  <<<dim3(NP/16, NB),       64, 0, stream>>>(X, Whi, Wlo, bq, bk, bv,
                                                          Qhi,Qlo, Khi,Klo, Vthi,Vtlo);
  stats_kernel <<<dim3(NP/128, 4, NB),  256, 0, stream>>>(Qhi,Qlo, Khi,Klo, colpart);
  scalev_kernel<<<dim3(n/(256*8)),      256, 0, stream>>>(Vthi, Vtlo, colpart);
  attn_kernel  <<<dim3(NP/128, 4, NB),  256, 0, stream>>>(Qhi,Qlo, Khi,Klo,
                                                          Vthi,Vtlo, xacc);
  final_kernel <<<dim3(n/(256*4)),      256, 0, stream>>>(X, xacc, outp);
}